// Round 4
// baseline (111.349 us; speedup 1.0000x reference)
//
#include <hip/hip_runtime.h>

#define NL 17
#define IGN (-100)
#define HD 384
#define NSEQ 1024
#define NT 65536
#define BIGI NT
#define TPB 256
#define NBLK_MAIN (NT / TPB)   // 256
#define NBLK_SCAN 64
#define NCHUNK 12              // 384 / 32
#define CCOLS 32
#define CF4 8                  // float4 per row per chunk

struct WS {
  float ce_part[NBLK_MAIN];
  float ctx_part[NBLK_MAIN];
  int   ce_cnt[NBLK_MAIN];
  int   ctx_cnt[NBLK_MAIN];
  int   blk_a[NBLK_SCAN][16];
  int   blk_p[NBLK_SCAN][16];
  int   blk_c[NBLK_SCAN][16];
  int   blk_d[NBLK_SCAN];
};

// ---------------- scan: per-block label stats ----------------
__global__ __launch_bounds__(256) void k_scan(const int* __restrict__ labels,
                                              const int* __restrict__ mask,
                                              WS* __restrict__ ws) {
  __shared__ int comp[1024];
  __shared__ int la[16], lc[16], lp[16], ld;
  const int tid = threadIdx.x, b = blockIdx.x;
  if (tid < 16) { la[tid] = BIGI; lc[tid] = 0; lp[tid] = BIGI; }
  if (tid == 16) ld = BIGI;
  __syncthreads();
  const int base = b * 1024;
#pragma unroll
  for (int k = 0; k < 4; ++k) {
    int l = tid + 256 * k, t = base + l;
    int lb = labels[t];
    int mk = mask[t];
    comp[l] = (mk > 0) ? lb : IGN;
    if (mk > 0) {
      if (lb == 0) atomicMin(&ld, t);
      else if (lb >= 1 && lb < NL) { atomicMin(&la[lb - 1], t); atomicAdd(&lc[lb - 1], 1); }
    }
  }
  __syncthreads();
#pragma unroll
  for (int k = 0; k < 4; ++k) {
    int l = tid + 256 * k, t = base + l;
    int c = comp[l];
    if (c >= 1 && c < NL && t > la[c - 1]) atomicMin(&lp[c - 1], t);
  }
  __syncthreads();
  if (tid < 16) {
    ws->blk_a[b][tid] = la[tid];
    ws->blk_p[b][tid] = lp[tid];
    ws->blk_c[b][tid] = lc[tid];
  }
  if (tid == 16) ws->blk_d[b] = ld;
}

// ---------------- main: LDS double-buffered coalesced streaming ----------------
__global__ __launch_bounds__(256, 1) void k_main(const float* __restrict__ emb,
                                                 const float* __restrict__ cw,
                                                 const float* __restrict__ cb,
                                                 const int* __restrict__ labels,
                                                 WS* __restrict__ ws) {
  __shared__ float4 tile[2][TPB][CF4];   // 64 KB double buffer
  __shared__ float sce[4], sctx[4];
  __shared__ int   svc[4], spc[4];
  __shared__ float sbctx;
  __shared__ int   sbcnt;

  const int tid = threadIdx.x, lane = tid & 63, wid = tid >> 6;
  const int b = blockIdx.x;
  const int token = b * TPB + tid;
  const float4* __restrict__ emb4 = (const float4*)emb;
  const size_t base4 = (size_t)b * TPB * (HD / 4);

  // staging coords: l = tid + k*256 -> row = rbase + k*32, c4 = tid&7 (const)
  const int rbase = tid >> 3;
  const int c4    = tid & 7;
  const int wslot = c4 ^ (rbase & 7);          // write swizzle (const per thread)
  const int r0 = tid;
  const int r1 = (tid < TPB - 1) ? tid + 1 : tid;
  const int s0x = r0 & 7, s1x = r1 & 7;        // read swizzle xor per row

  float acc[NL];
#pragma unroll
  for (int c = 0; c < NL; ++c) acc[c] = 0.f;
  float ctxacc = 0.f;

  // prefetch chunk 0 into registers
  float4 pf[CF4];
#pragma unroll
  for (int k = 0; k < CF4; ++k)
    pf[k] = emb4[base4 + (size_t)(rbase + k * 32) * (HD / 4) + c4];

#pragma unroll 1
  for (int ch = 0; ch < NCHUNK; ++ch) {
    float4 (* __restrict__ tb)[CF4] = tile[ch & 1];
    // store chunk ch (compiler inserts counted vmcnt for pf)
#pragma unroll
    for (int k = 0; k < CF4; ++k) tb[rbase + k * 32][wslot] = pf[k];
    __syncthreads();
    // issue chunk ch+1 loads (in flight across the compute below)
    if (ch + 1 < NCHUNK) {
#pragma unroll
      for (int k = 0; k < CF4; ++k)
        pf[k] = emb4[base4 + (size_t)(rbase + k * 32) * (HD / 4) + (ch + 1) * CF4 + c4];
    }
    // compute chunk ch from LDS, one float4 at a time (small live set)
    const float* wch = cw + ch * CCOLS;
#pragma unroll
    for (int q = 0; q < CF4; ++q) {
      float4 a  = tb[r0][q ^ s0x];
      float4 nb = tb[r1][q ^ s1x];
      float d0 = a.x - nb.x, d1 = a.y - nb.y, d2 = a.z - nb.z, d3 = a.w - nb.w;
      ctxacc = fmaf(d0, d0, ctxacc); ctxacc = fmaf(d1, d1, ctxacc);
      ctxacc = fmaf(d2, d2, ctxacc); ctxacc = fmaf(d3, d3, ctxacc);
      const float* w4 = wch + q * 4;            // wave-uniform -> scalar loads
#pragma unroll
      for (int c = 0; c < NL; ++c) {
        const float* wr = w4 + c * HD;
        acc[c] = fmaf(a.x, wr[0],
                 fmaf(a.y, wr[1],
                 fmaf(a.z, wr[2],
                 fmaf(a.w, wr[3], acc[c]))));
      }
    }
  }

  // ---- epilogue: softmax + CE + ctx pair, block reduce ----
  float m = acc[0] + cb[0];
#pragma unroll
  for (int c = 0; c < NL; ++c) acc[c] += cb[c];
#pragma unroll
  for (int c = 1; c < NL; ++c) m = fmaxf(m, acc[c]);
  float s = 0.f;
#pragma unroll
  for (int c = 0; c < NL; ++c) s += __expf(acc[c] - m);
  float lse = m + __logf(s);
  int lb = labels[token];
  int safe = (lb == IGN) ? 0 : lb;
  float ll = 0.f;
#pragma unroll
  for (int c = 0; c < NL; ++c) ll = (c == safe) ? acc[c] : ll;
  bool valid = (lb != IGN);
  float cev = valid ? (lse - ll) : 0.f;

  int nlb = (tid < TPB - 1) ? labels[token + 1] : IGN;
  bool pair = (tid < TPB - 1) && valid && (lb == nlb) && (lb > 0);
  float ctxv = pair ? ctxacc * (1.0f / HD) : 0.f;

  unsigned long long bv = __ballot(valid);
  unsigned long long bp = __ballot(pair);
#pragma unroll
  for (int off = 32; off; off >>= 1) {
    cev  += __shfl_xor(cev, off, 64);
    ctxv += __shfl_xor(ctxv, off, 64);
  }
  if (lane == 0) { sce[wid] = cev; sctx[wid] = ctxv; svc[wid] = __popcll(bv); spc[wid] = __popcll(bp); }

  if (wid == 3) {   // cross-block boundary pair (b*256+255, b*256+256)
    int t = b * TPB + TPB - 1;
    float bc = 0.f; int bn = 0;
    if (((t + 1) & (NSEQ - 1)) != 0) {
      int l0 = labels[t], l1 = labels[t + 1];
      if (l0 != IGN && l0 == l1 && l0 > 0) {
        const float* ra = emb + (size_t)t * HD;
        const float* rb = ra + HD;
        float a = 0.f;
#pragma unroll
        for (int j = 0; j < 6; ++j) {
          float d = ra[lane + 64 * j] - rb[lane + 64 * j];
          a = fmaf(d, d, a);
        }
#pragma unroll
        for (int off = 32; off; off >>= 1) a += __shfl_xor(a, off, 64);
        bc = a * (1.0f / HD); bn = 1;
      }
    }
    if (lane == 0) { sbctx = bc; sbcnt = bn; }
  }
  __syncthreads();
  if (tid == 0) {
    ws->ce_part[b]  = sce[0] + sce[1] + sce[2] + sce[3];
    ws->ce_cnt[b]   = svc[0] + svc[1] + svc[2] + svc[3];
    ws->ctx_part[b] = sctx[0] + sctx[1] + sctx[2] + sctx[3] + sbctx;
    ws->ctx_cnt[b]  = spc[0] + spc[1] + spc[2] + spc[3] + sbcnt;
  }
}

// ---------------- finalize ----------------
__global__ __launch_bounds__(256) void k_final(const float* __restrict__ emb,
                                               WS* __restrict__ ws,
                                               float* __restrict__ out) {
  __shared__ double rce[256], rctx[256];
  __shared__ int rvc[256], rpc[256];
  __shared__ int ga[16], gp[16], gc[16];
  __shared__ int gdsh;
  __shared__ float qs[4]; __shared__ int qc[4];
  const int tid = threadIdx.x, lane = tid & 63, wid = tid >> 6;

  rce[tid]  = ws->ce_part[tid];
  rctx[tid] = ws->ctx_part[tid];
  rvc[tid]  = ws->ce_cnt[tid];
  rpc[tid]  = ws->ctx_cnt[tid];
  __syncthreads();
  for (int s = 128; s > 0; s >>= 1) {
    if (tid < s) {
      rce[tid] += rce[tid + s]; rctx[tid] += rctx[tid + s];
      rvc[tid] += rvc[tid + s]; rpc[tid] += rpc[tid + s];
    }
    __syncthreads();
  }

  if (tid < 16) {
    int m1 = BIGI, m2 = BIGI, cnt = 0;
    for (int bb = 0; bb < NBLK_SCAN; ++bb) {
      int x = ws->blk_a[bb][tid];
      if (x < m1) { m2 = m1; m1 = x; } else if (x < m2) { m2 = x; }
      int y = ws->blk_p[bb][tid];
      if (y < m1) { m2 = m1; m1 = y; } else if (y < m2) { m2 = y; }
      cnt += ws->blk_c[bb][tid];
    }
    ga[tid] = m1; gp[tid] = m2; gc[tid] = cnt;
  }
  if (tid == 16) {
    int d = BIGI;
    for (int bb = 0; bb < NBLK_SCAN; ++bb) d = min(d, ws->blk_d[bb]);
    gdsh = d;
  }
  __syncthreads();

  const int gd = gdsh;
  float qsum = 0.f; int qcnt = 0;
  for (int tt = 0; tt < 4; ++tt) {
    int t = wid * 4 + tt;
    int a = ga[t], p = gp[t], c = gc[t];
    int nmin = BIGI;
#pragma unroll
    for (int u = 0; u < 16; ++u) if (u != t) nmin = min(nmin, ga[u]);
    bool ok = (c >= 2) && (nmin < BIGI) && (gd < BIGI);
    if (ok) {
      const float* A  = emb + (size_t)min(a, NT - 1) * HD;
      const float* P  = emb + (size_t)min(p, NT - 1) * HD;
      const float* Ng = emb + (size_t)min(nmin, NT - 1) * HD;
      const float* D  = emb + (size_t)min(gd, NT - 1) * HD;
      float sap = 0.f, san = 0.f, sad = 0.f;
#pragma unroll
      for (int j = 0; j < 6; ++j) {
        int idx = lane + 64 * j;
        float av = A[idx];
        float d1 = av - P[idx] + 1e-6f;  sap = fmaf(d1, d1, sap);
        float d2 = av - Ng[idx] + 1e-6f; san = fmaf(d2, d2, san);
        float d3 = av - D[idx] + 1e-6f;  sad = fmaf(d3, d3, sad);
      }
#pragma unroll
      for (int off = 32; off; off >>= 1) {
        sap += __shfl_xor(sap, off, 64);
        san += __shfl_xor(san, off, 64);
        sad += __shfl_xor(sad, off, 64);
      }
      float pd = sqrtf(sap), nd = sqrtf(san), dd = sqrtf(sad);
      qsum += fmaxf(pd - nd + 1.0f, 0.f) + fmaxf(pd - dd + 2.0f, 0.f);
      qcnt += 1;
    }
  }
  if (lane == 0) { qs[wid] = qsum; qc[wid] = qcnt; }
  __syncthreads();
  if (tid == 0) {
    double tq = (double)qs[0] + qs[1] + qs[2] + qs[3];
    int tqc = qc[0] + qc[1] + qc[2] + qc[3];
    double ce   = rce[0] / (double)max(rvc[0], 1);
    double ctx  = (rpc[0] > 0) ? rctx[0] / (double)rpc[0] : 0.0;
    double quad = (tqc > 0) ? tq / (double)tqc : 0.0;
    out[0] = (float)(ce + 0.5 * quad + 0.1 * ctx);
  }
}

extern "C" void kernel_launch(void* const* d_in, const int* in_sizes, int n_in,
                              void* d_out, int out_size, void* d_ws, size_t ws_size,
                              hipStream_t stream) {
  const float* emb    = (const float*)d_in[0];
  const float* cw     = (const float*)d_in[1];
  const float* cb     = (const float*)d_in[2];
  const int*   labels = (const int*)d_in[3];
  const int*   mask   = (const int*)d_in[4];
  WS* ws = (WS*)d_ws;
  float* out = (float*)d_out;

  k_scan <<<NBLK_SCAN, 256, 0, stream>>>(labels, mask, ws);
  k_main <<<NBLK_MAIN, 256, 0, stream>>>(emb, cw, cb, labels, ws);
  k_final<<<1, 256, 0, stream>>>(emb, ws, out);
}

// Round 5
// 85.022 us; speedup vs baseline: 1.3096x; 1.3096x over previous
//
#include <hip/hip_runtime.h>

#define NL 17
#define IGN (-100)
#define HD 384
#define NSEQ 1024
#define NT 65536
#define BIGI NT
#define TPB 256
#define NBLK_MAIN (NT / TPB)   // 256
#define NBLK_SCAN 64
#define NCHUNK 12              // 384 / 32 cols
#define CF4 8                  // float4 per row per chunk

typedef unsigned int u32;

// HBM -> LDS direct (16B per lane); LDS dest is wave-uniform base + lane*16
#define GLOAD_LDS16(g, l) __builtin_amdgcn_global_load_lds(                    \
    (const __attribute__((address_space(1))) u32*)(g),                         \
    (__attribute__((address_space(3))) u32*)(l), 16, 0, 0)

struct WS {
  float ce_part[NBLK_MAIN];
  float ctx_part[NBLK_MAIN];
  int   ce_cnt[NBLK_MAIN];
  int   ctx_cnt[NBLK_MAIN];
  int   blk_a[NBLK_SCAN][16];
  int   blk_p[NBLK_SCAN][16];
  int   blk_c[NBLK_SCAN][16];
  int   blk_d[NBLK_SCAN];
};

// ---------------- scan: per-block label stats ----------------
__global__ __launch_bounds__(256) void k_scan(const int* __restrict__ labels,
                                              const int* __restrict__ mask,
                                              WS* __restrict__ ws) {
  __shared__ int comp[1024];
  __shared__ int la[16], lc[16], lp[16], ld;
  const int tid = threadIdx.x, b = blockIdx.x;
  if (tid < 16) { la[tid] = BIGI; lc[tid] = 0; lp[tid] = BIGI; }
  if (tid == 16) ld = BIGI;
  __syncthreads();
  const int base = b * 1024;
#pragma unroll
  for (int k = 0; k < 4; ++k) {
    int l = tid + 256 * k, t = base + l;
    int lb = labels[t];
    int mk = mask[t];
    comp[l] = (mk > 0) ? lb : IGN;
    if (mk > 0) {
      if (lb == 0) atomicMin(&ld, t);
      else if (lb >= 1 && lb < NL) { atomicMin(&la[lb - 1], t); atomicAdd(&lc[lb - 1], 1); }
    }
  }
  __syncthreads();
#pragma unroll
  for (int k = 0; k < 4; ++k) {
    int l = tid + 256 * k, t = base + l;
    int c = comp[l];
    if (c >= 1 && c < NL && t > la[c - 1]) atomicMin(&lp[c - 1], t);
  }
  __syncthreads();
  if (tid < 16) {
    ws->blk_a[b][tid] = la[tid];
    ws->blk_p[b][tid] = lp[tid];
    ws->blk_c[b][tid] = lc[tid];
  }
  if (tid == 16) ws->blk_d[b] = ld;
}

// ---------------- main: global_load_lds double-buffer, counted vmcnt ----------------
__global__ __launch_bounds__(256, 1) void k_main(const float* __restrict__ emb,
                                                 const float* __restrict__ cw,
                                                 const float* __restrict__ cb,
                                                 const int* __restrict__ labels,
                                                 WS* __restrict__ ws) {
  __shared__ float4 tile[2][TPB * CF4];   // 2 x 32 KB, linear (gload_lds dest)
  __shared__ float4 sW[NL * (HD / 4)];    // 17 x 96 f4 = 25.5 KB
  __shared__ float sce[4], sctx[4];
  __shared__ int   svc[4], spc[4];
  __shared__ float sbctx;
  __shared__ int   sbcnt;

  const int tid = threadIdx.x, lane = tid & 63, wid = tid >> 6;
  const int b = blockIdx.x;
  const int token = b * TPB + tid;

  // ---- W -> LDS (once) ----
  const float4* cw4 = (const float4*)cw;
#pragma unroll
  for (int i = tid; i < NL * (HD / 4); i += TPB) sW[i] = cw4[i];

  // ---- staging geometry ----
  // slot s = k*256 + tid holds f4 # (row*96 + ch*8 + (c4 ^ (row&7))), row = k*32 + (tid>>3)
  const int rb  = tid >> 3;
  const int c4  = tid & 7;
  const int gc4 = c4 ^ (rb & 7);          // swizzled source column (const per thread)
  const float* src0 = emb + (size_t)b * TPB * HD + (size_t)rb * HD + gc4 * 4;
  const int wbase = __builtin_amdgcn_readfirstlane(wid * 64);  // wave-uniform LDS f4 base

  // issue chunk 0
#pragma unroll
  for (int k = 0; k < CF4; ++k)
    GLOAD_LDS16(src0 + (size_t)k * 32 * HD, &tile[0][k * 256 + wbase]);

  __syncthreads();   // one-time prologue drain: W writes + chunk0 visible

  float acc[NL];
#pragma unroll
  for (int c = 0; c < NL; ++c) acc[c] = 0.f;
  float ctxacc = 0.f;

  const int r0 = tid;
  const int r1 = (tid < TPB - 1) ? tid + 1 : tid;   // neighbor row (clamped)
  const int x0 = r0 & 7, x1 = r1 & 7;

  auto compute = [&](int ch, const float4* tb) {
    const float4* wch = &sW[ch * CF4];   // sW[c*96 + ch*8 + q]
#pragma unroll
    for (int q = 0; q < CF4; ++q) {
      float4 a  = tb[(r0 << 3) | (q ^ x0)];
      float4 nb = tb[(r1 << 3) | (q ^ x1)];
      float d0 = a.x - nb.x, d1 = a.y - nb.y, d2 = a.z - nb.z, d3 = a.w - nb.w;
      ctxacc = fmaf(d0, d0, fmaf(d1, d1, fmaf(d2, d2, fmaf(d3, d3, ctxacc))));
#pragma unroll
      for (int c = 0; c < NL; ++c) {
        float4 w = wch[c * (HD / 4) + q];   // uniform addr -> LDS broadcast
        acc[c] = fmaf(a.x, w.x, fmaf(a.y, w.y, fmaf(a.z, w.z, fmaf(a.w, w.w, acc[c]))));
      }
    }
  };

#pragma unroll 1
  for (int ch = 0; ch < NCHUNK - 1; ++ch) {
    // issue chunk ch+1 into the other buffer (stays in flight across the barrier)
    const float* srcn = src0 + (size_t)(ch + 1) * 32;
    float4* dstb = tile[(ch + 1) & 1];
#pragma unroll
    for (int k = 0; k < CF4; ++k)
      GLOAD_LDS16(srcn + (size_t)k * 32 * HD, &dstb[k * 256 + wbase]);
    // oldest 8 (chunk ch) complete; newest 8 (chunk ch+1) may stay outstanding
    asm volatile("s_waitcnt vmcnt(8)" ::: "memory");
    __builtin_amdgcn_sched_barrier(0);
    __builtin_amdgcn_s_barrier();
    __builtin_amdgcn_sched_barrier(0);
    compute(ch, tile[ch & 1]);
    __builtin_amdgcn_s_barrier();   // all reads of tile[ch&1] done before next overwrite
  }
  asm volatile("s_waitcnt vmcnt(0)" ::: "memory");
  __builtin_amdgcn_sched_barrier(0);
  __builtin_amdgcn_s_barrier();
  __builtin_amdgcn_sched_barrier(0);
  compute(NCHUNK - 1, tile[(NCHUNK - 1) & 1]);

  // ---- epilogue: softmax + CE + ctx pair, block reduce ----
  float m = acc[0] + cb[0];
#pragma unroll
  for (int c = 0; c < NL; ++c) acc[c] += cb[c];
#pragma unroll
  for (int c = 1; c < NL; ++c) m = fmaxf(m, acc[c]);
  float s = 0.f;
#pragma unroll
  for (int c = 0; c < NL; ++c) s += __expf(acc[c] - m);
  float lse = m + __logf(s);
  int lb = labels[token];
  int safe = (lb == IGN) ? 0 : lb;
  float ll = 0.f;
#pragma unroll
  for (int c = 0; c < NL; ++c) ll = (c == safe) ? acc[c] : ll;
  bool valid = (lb != IGN);
  float cev = valid ? (lse - ll) : 0.f;

  int nlb = (tid < TPB - 1) ? labels[token + 1] : IGN;
  bool pair = (tid < TPB - 1) && valid && (lb == nlb) && (lb > 0);
  float ctxv = pair ? ctxacc * (1.0f / HD) : 0.f;

  unsigned long long bv = __ballot(valid);
  unsigned long long bp = __ballot(pair);
#pragma unroll
  for (int off = 32; off; off >>= 1) {
    cev  += __shfl_xor(cev, off, 64);
    ctxv += __shfl_xor(ctxv, off, 64);
  }
  if (lane == 0) { sce[wid] = cev; sctx[wid] = ctxv; svc[wid] = __popcll(bv); spc[wid] = __popcll(bp); }

  if (wid == 3) {   // cross-block boundary pair (b*256+255, b*256+256)
    int t = b * TPB + TPB - 1;
    float bc = 0.f; int bn = 0;
    if (((t + 1) & (NSEQ - 1)) != 0) {
      int l0 = labels[t], l1 = labels[t + 1];
      if (l0 != IGN && l0 == l1 && l0 > 0) {
        const float* ra = emb + (size_t)t * HD;
        const float* rbp = ra + HD;
        float a = 0.f;
#pragma unroll
        for (int j = 0; j < 6; ++j) {
          float d = ra[lane + 64 * j] - rbp[lane + 64 * j];
          a = fmaf(d, d, a);
        }
#pragma unroll
        for (int off = 32; off; off >>= 1) a += __shfl_xor(a, off, 64);
        bc = a * (1.0f / HD); bn = 1;
      }
    }
    if (lane == 0) { sbctx = bc; sbcnt = bn; }
  }
  __syncthreads();
  if (tid == 0) {
    ws->ce_part[b]  = sce[0] + sce[1] + sce[2] + sce[3];
    ws->ce_cnt[b]   = svc[0] + svc[1] + svc[2] + svc[3];
    ws->ctx_part[b] = sctx[0] + sctx[1] + sctx[2] + sctx[3] + sbctx;
    ws->ctx_cnt[b]  = spc[0] + spc[1] + spc[2] + spc[3] + sbcnt;
  }
}

// ---------------- finalize ----------------
__global__ __launch_bounds__(256) void k_final(const float* __restrict__ emb,
                                               WS* __restrict__ ws,
                                               float* __restrict__ out) {
  __shared__ double rce[256], rctx[256];
  __shared__ int rvc[256], rpc[256];
  __shared__ int ga[16], gp[16], gc[16];
  __shared__ int gdsh;
  __shared__ float qs[4]; __shared__ int qc[4];
  const int tid = threadIdx.x, lane = tid & 63, wid = tid >> 6;

  rce[tid]  = ws->ce_part[tid];
  rctx[tid] = ws->ctx_part[tid];
  rvc[tid]  = ws->ce_cnt[tid];
  rpc[tid]  = ws->ctx_cnt[tid];
  __syncthreads();
  for (int s = 128; s > 0; s >>= 1) {
    if (tid < s) {
      rce[tid] += rce[tid + s]; rctx[tid] += rctx[tid + s];
      rvc[tid] += rvc[tid + s]; rpc[tid] += rpc[tid + s];
    }
    __syncthreads();
  }

  if (tid < 16) {
    int m1 = BIGI, m2 = BIGI, cnt = 0;
    for (int bb = 0; bb < NBLK_SCAN; ++bb) {
      int x = ws->blk_a[bb][tid];
      if (x < m1) { m2 = m1; m1 = x; } else if (x < m2) { m2 = x; }
      int y = ws->blk_p[bb][tid];
      if (y < m1) { m2 = m1; m1 = y; } else if (y < m2) { m2 = y; }
      cnt += ws->blk_c[bb][tid];
    }
    ga[tid] = m1; gp[tid] = m2; gc[tid] = cnt;
  }
  if (tid == 16) {
    int d = BIGI;
    for (int bb = 0; bb < NBLK_SCAN; ++bb) d = min(d, ws->blk_d[bb]);
    gdsh = d;
  }
  __syncthreads();

  const int gd = gdsh;
  float qsum = 0.f; int qcnt = 0;
  for (int tt = 0; tt < 4; ++tt) {
    int t = wid * 4 + tt;
    int a = ga[t], p = gp[t], c = gc[t];
    int nmin = BIGI;
#pragma unroll
    for (int u = 0; u < 16; ++u) if (u != t) nmin = min(nmin, ga[u]);
    bool ok = (c >= 2) && (nmin < BIGI) && (gd < BIGI);
    if (ok) {
      const float* A  = emb + (size_t)min(a, NT - 1) * HD;
      const float* P  = emb + (size_t)min(p, NT - 1) * HD;
      const float* Ng = emb + (size_t)min(nmin, NT - 1) * HD;
      const float* D  = emb + (size_t)min(gd, NT - 1) * HD;
      float sap = 0.f, san = 0.f, sad = 0.f;
#pragma unroll
      for (int j = 0; j < 6; ++j) {
        int idx = lane + 64 * j;
        float av = A[idx];
        float d1 = av - P[idx] + 1e-6f;  sap = fmaf(d1, d1, sap);
        float d2 = av - Ng[idx] + 1e-6f; san = fmaf(d2, d2, san);
        float d3 = av - D[idx] + 1e-6f;  sad = fmaf(d3, d3, sad);
      }
#pragma unroll
      for (int off = 32; off; off >>= 1) {
        sap += __shfl_xor(sap, off, 64);
        san += __shfl_xor(san, off, 64);
        sad += __shfl_xor(sad, off, 64);
      }
      float pd = sqrtf(sap), nd = sqrtf(san), dd = sqrtf(sad);
      qsum += fmaxf(pd - nd + 1.0f, 0.f) + fmaxf(pd - dd + 2.0f, 0.f);
      qcnt += 1;
    }
  }
  if (lane == 0) { qs[wid] = qsum; qc[wid] = qcnt; }
  __syncthreads();
  if (tid == 0) {
    double tq = (double)qs[0] + qs[1] + qs[2] + qs[3];
    int tqc = qc[0] + qc[1] + qc[2] + qc[3];
    double ce   = rce[0] / (double)max(rvc[0], 1);
    double ctx  = (rpc[0] > 0) ? rctx[0] / (double)rpc[0] : 0.0;
    double quad = (tqc > 0) ? tq / (double)tqc : 0.0;
    out[0] = (float)(ce + 0.5 * quad + 0.1 * ctx);
  }
}

extern "C" void kernel_launch(void* const* d_in, const int* in_sizes, int n_in,
                              void* d_out, int out_size, void* d_ws, size_t ws_size,
                              hipStream_t stream) {
  const float* emb    = (const float*)d_in[0];
  const float* cw     = (const float*)d_in[1];
  const float* cb     = (const float*)d_in[2];
  const int*   labels = (const int*)d_in[3];
  const int*   mask   = (const int*)d_in[4];
  WS* ws = (WS*)d_ws;
  float* out = (float*)d_out;

  k_scan <<<NBLK_SCAN, 256, 0, stream>>>(labels, mask, ws);
  k_main <<<NBLK_MAIN, 256, 0, stream>>>(emb, cw, cb, labels, ws);
  k_final<<<1, 256, 0, stream>>>(emb, ws, out);
}

// Round 6
// 45.402 us; speedup vs baseline: 2.4525x; 1.8726x over previous
//
#include <hip/hip_runtime.h>

#define NL 17
#define IGN (-100)
#define HD 384
#define NSEQ 1024
#define NT 65536
#define BIGI NT
#define TPB 256
#define NBLK_MAIN (NT / TPB)   // 256
#define NBLK_SCAN 64
#define NCHUNK 12              // 384 / 32 cols
#define CF4 8                  // float4 per row per chunk

typedef unsigned int u32;
typedef __attribute__((ext_vector_type(8))) short bf16x8;
typedef __attribute__((ext_vector_type(16))) float f32x16;

#define GLOAD_LDS16(g, l) __builtin_amdgcn_global_load_lds(                    \
    (const __attribute__((address_space(1))) u32*)(g),                         \
    (__attribute__((address_space(3))) u32*)(l), 16, 0, 0)

__device__ __forceinline__ u32 cvtpk(float lo, float hi) {
  u32 u;
  asm("v_cvt_pk_bf16_f32 %0, %1, %2" : "=v"(u) : "v"(lo), "v"(hi));
  return u;
}

struct WS {
  float ce_part[NBLK_MAIN];
  float ctx_part[NBLK_MAIN];
  int   ce_cnt[NBLK_MAIN];
  int   ctx_cnt[NBLK_MAIN];
  int   blk_a[NBLK_SCAN][16];
  int   blk_p[NBLK_SCAN][16];
  int   blk_c[NBLK_SCAN][16];
  int   blk_d[NBLK_SCAN];
};

// ---------------- scan: per-block label stats ----------------
__global__ __launch_bounds__(256) void k_scan(const int* __restrict__ labels,
                                              const int* __restrict__ mask,
                                              WS* __restrict__ ws) {
  __shared__ int comp[1024];
  __shared__ int la[16], lc[16], lp[16], ld;
  const int tid = threadIdx.x, b = blockIdx.x;
  if (tid < 16) { la[tid] = BIGI; lc[tid] = 0; lp[tid] = BIGI; }
  if (tid == 16) ld = BIGI;
  __syncthreads();
  const int base = b * 1024;
#pragma unroll
  for (int k = 0; k < 4; ++k) {
    int l = tid + 256 * k, t = base + l;
    int lb = labels[t];
    int mk = mask[t];
    comp[l] = (mk > 0) ? lb : IGN;
    if (mk > 0) {
      if (lb == 0) atomicMin(&ld, t);
      else if (lb >= 1 && lb < NL) { atomicMin(&la[lb - 1], t); atomicAdd(&lc[lb - 1], 1); }
    }
  }
  __syncthreads();
#pragma unroll
  for (int k = 0; k < 4; ++k) {
    int l = tid + 256 * k, t = base + l;
    int c = comp[l];
    if (c >= 1 && c < NL && t > la[c - 1]) atomicMin(&lp[c - 1], t);
  }
  __syncthreads();
  if (tid < 16) {
    ws->blk_a[b][tid] = la[tid];
    ws->blk_p[b][tid] = lp[tid];
    ws->blk_c[b][tid] = lc[tid];
  }
  if (tid == 16) ws->blk_d[b] = ld;
}

// ---------------- main: gload_lds staging + MFMA 32x32x16 bf16 GEMM ----------------
__global__ __launch_bounds__(256, 1) void k_main(const float* __restrict__ emb,
                                                 const float* __restrict__ cw,
                                                 const float* __restrict__ cb,
                                                 const int* __restrict__ labels,
                                                 WS* __restrict__ ws) {
  __shared__ float4 tile[2][TPB * CF4];   // 2 x 32 KB, linear (gload_lds dest)
  __shared__ float4 sW4[NL * (HD / 4)];   // 25.5 KB, granule-swizzled W
  __shared__ float sce[4], sctx[4];
  __shared__ int   svc[4], spc[4];
  __shared__ float sbctx;
  __shared__ int   sbcnt;

  const int tid = threadIdx.x, lane = tid & 63, wid = tid >> 6;
  const int b = blockIdx.x;
  const int token = b * TPB + tid;

  // ---- W -> LDS (once), granule-swizzled: phys q = q ^ (c&7) ----
  const float4* cw4 = (const float4*)cw;
  for (int i = tid; i < NL * (HD / 4); i += TPB) {
    int c = i / (HD / 4), q = i % (HD / 4);
    sW4[c * (HD / 4) + (q ^ (c & 7))] = cw4[i];
  }
  __syncthreads();

  // ---- staging geometry (round-5 proven) ----
  const int rb  = tid >> 3;
  const int c4  = tid & 7;
  const int gc4 = c4 ^ (rb & 7);          // pre-swizzled source column
  const float* src0 = emb + (size_t)b * TPB * HD + (size_t)rb * HD + gc4 * 4;
  const int wbase = __builtin_amdgcn_readfirstlane(wid * 64);

#pragma unroll
  for (int k = 0; k < CF4; ++k)
    GLOAD_LDS16(src0 + (size_t)k * 32 * HD, &tile[0][k * 256 + wbase]);

  // ---- MFMA geometry ----
  const int cls = lane & 31;              // A: class row (17..31 are pad)
  const int kh  = lane >> 5;              // k-half (0: k0-7, 1: k8-15)
  const int clsS = (cls < NL) ? cls : 0;  // safe gather class
  const int row0 = wid * 64 + (lane & 31);        // B tile0 token row
  const int row1 = row0 + 32;                     // B tile1 token row
  const int r0 = tid;
  const int r1 = (tid < TPB - 1) ? tid + 1 : tid; // ctx neighbor row
  const int x0 = r0 & 7, x1 = r1 & 7;

  f32x16 d0 = {0.f}, d1 = {0.f};
  float ctxacc = 0.f;

  auto bfrag = [&](const float4* tb, int row, int s) -> bf16x8 {
    int g0 = (s * 4 + kh * 2) ^ (row & 7);
    int g1 = (s * 4 + kh * 2 + 1) ^ (row & 7);
    float4 f0 = tb[(row << 3) | g0];
    float4 f1 = tb[(row << 3) | g1];
    union { u32 u[4]; bf16x8 v; } X;
    X.u[0] = cvtpk(f0.x, f0.y); X.u[1] = cvtpk(f0.z, f0.w);
    X.u[2] = cvtpk(f1.x, f1.y); X.u[3] = cvtpk(f1.z, f1.w);
    return X.v;
  };

  auto afrag = [&](int ch, int s) -> bf16x8 {
    union { u32 u[4]; bf16x8 v; } X;
    if (cls < NL) {
      int qa = (ch * 2 + s) * 4 + kh * 2;
      float4 f0 = sW4[clsS * (HD / 4) + ((qa) ^ (cls & 7))];
      float4 f1 = sW4[clsS * (HD / 4) + ((qa + 1) ^ (cls & 7))];
      X.u[0] = cvtpk(f0.x, f0.y); X.u[1] = cvtpk(f0.z, f0.w);
      X.u[2] = cvtpk(f1.x, f1.y); X.u[3] = cvtpk(f1.z, f1.w);
    } else {
      X.u[0] = 0; X.u[1] = 0; X.u[2] = 0; X.u[3] = 0;
    }
    return X.v;
  };

  auto compute = [&](int ch, const float4* tb) {
    // ctx MSE partial (fp32, own vs neighbor row)
#pragma unroll
    for (int q = 0; q < CF4; ++q) {
      float4 a  = tb[(r0 << 3) | (q ^ x0)];
      float4 nb = tb[(r1 << 3) | (q ^ x1)];
      float e0 = a.x - nb.x, e1 = a.y - nb.y, e2 = a.z - nb.z, e3 = a.w - nb.w;
      ctxacc = fmaf(e0, e0, fmaf(e1, e1, fmaf(e2, e2, fmaf(e3, e3, ctxacc))));
    }
    // GEMM slice: 2 k-steps x 2 token-tiles
    bf16x8 a0 = afrag(ch, 0), a1 = afrag(ch, 1);
    bf16x8 b00 = bfrag(tb, row0, 0), b01 = bfrag(tb, row0, 1);
    bf16x8 b10 = bfrag(tb, row1, 0), b11 = bfrag(tb, row1, 1);
    d0 = __builtin_amdgcn_mfma_f32_32x32x16_bf16(a0, b00, d0, 0, 0, 0);
    d0 = __builtin_amdgcn_mfma_f32_32x32x16_bf16(a1, b01, d0, 0, 0, 0);
    d1 = __builtin_amdgcn_mfma_f32_32x32x16_bf16(a0, b10, d1, 0, 0, 0);
    d1 = __builtin_amdgcn_mfma_f32_32x32x16_bf16(a1, b11, d1, 0, 0, 0);
  };

#pragma unroll 1
  for (int ch = 0; ch < NCHUNK - 1; ++ch) {
    const float* srcn = src0 + (size_t)(ch + 1) * 32;
    float4* dstb = tile[(ch + 1) & 1];
#pragma unroll
    for (int k = 0; k < CF4; ++k)
      GLOAD_LDS16(srcn + (size_t)k * 32 * HD, &dstb[k * 256 + wbase]);
    asm volatile("s_waitcnt vmcnt(8)" ::: "memory");
    __builtin_amdgcn_sched_barrier(0);
    __builtin_amdgcn_s_barrier();
    __builtin_amdgcn_sched_barrier(0);
    compute(ch, tile[ch & 1]);
    __builtin_amdgcn_s_barrier();
  }
  asm volatile("s_waitcnt vmcnt(0)" ::: "memory");
  __builtin_amdgcn_sched_barrier(0);
  __builtin_amdgcn_s_barrier();
  __builtin_amdgcn_sched_barrier(0);
  compute(NCHUNK - 1, tile[(NCHUNK - 1) & 1]);
  __syncthreads();   // all tile reads done; tile[0] region becomes logits

  // ---- D -> LDS logits [256][21] (stride 21 spreads banks) ----
  float* logit = (float*)&tile[0][0];   // 256*21*4 = 21.5 KB < 32 KB
#pragma unroll
  for (int r = 0; r < 16; ++r) {
    int row = (r & 3) + 8 * (r >> 2) + 4 * kh;   // class
    if (row < NL) {
      logit[(wid * 64 + (lane & 31)) * 21 + row] = d0[r];
      logit[(wid * 64 + 32 + (lane & 31)) * 21 + row] = d1[r];
    }
  }
  __syncthreads();

  // ---- epilogue: softmax + CE + ctx pair, block reduce (round-5 verbatim) ----
  float lg[NL];
#pragma unroll
  for (int c = 0; c < NL; ++c) lg[c] = logit[tid * 21 + c] + cb[c];
  float m = lg[0];
#pragma unroll
  for (int c = 1; c < NL; ++c) m = fmaxf(m, lg[c]);
  float s = 0.f;
#pragma unroll
  for (int c = 0; c < NL; ++c) s += __expf(lg[c] - m);
  float lse = m + __logf(s);
  int lb = labels[token];
  int safe = (lb == IGN) ? 0 : lb;
  float ll = 0.f;
#pragma unroll
  for (int c = 0; c < NL; ++c) ll = (c == safe) ? lg[c] : ll;
  bool valid = (lb != IGN);
  float cev = valid ? (lse - ll) : 0.f;

  int nlb = (tid < TPB - 1) ? labels[token + 1] : IGN;
  bool pair = (tid < TPB - 1) && valid && (lb == nlb) && (lb > 0);
  float ctxv = pair ? ctxacc * (1.0f / HD) : 0.f;

  unsigned long long bv = __ballot(valid);
  unsigned long long bp = __ballot(pair);
#pragma unroll
  for (int off = 32; off; off >>= 1) {
    cev  += __shfl_xor(cev, off, 64);
    ctxv += __shfl_xor(ctxv, off, 64);
  }
  if (lane == 0) { sce[wid] = cev; sctx[wid] = ctxv; svc[wid] = __popcll(bv); spc[wid] = __popcll(bp); }

  if (wid == 3) {   // cross-block boundary pair (b*256+255, b*256+256)
    int t = b * TPB + TPB - 1;
    float bc = 0.f; int bn = 0;
    if (((t + 1) & (NSEQ - 1)) != 0) {
      int l0 = labels[t], l1 = labels[t + 1];
      if (l0 != IGN && l0 == l1 && l0 > 0) {
        const float* ra = emb + (size_t)t * HD;
        const float* rbp = ra + HD;
        float a = 0.f;
#pragma unroll
        for (int j = 0; j < 6; ++j) {
          float dd = ra[lane + 64 * j] - rbp[lane + 64 * j];
          a = fmaf(dd, dd, a);
        }
#pragma unroll
        for (int off = 32; off; off >>= 1) a += __shfl_xor(a, off, 64);
        bc = a * (1.0f / HD); bn = 1;
      }
    }
    if (lane == 0) { sbctx = bc; sbcnt = bn; }
  }
  __syncthreads();
  if (tid == 0) {
    ws->ce_part[b]  = sce[0] + sce[1] + sce[2] + sce[3];
    ws->ce_cnt[b]   = svc[0] + svc[1] + svc[2] + svc[3];
    ws->ctx_part[b] = sctx[0] + sctx[1] + sctx[2] + sctx[3] + sbctx;
    ws->ctx_cnt[b]  = spc[0] + spc[1] + spc[2] + spc[3] + sbcnt;
  }
}

// ---------------- finalize ----------------
__global__ __launch_bounds__(256) void k_final(const float* __restrict__ emb,
                                               WS* __restrict__ ws,
                                               float* __restrict__ out) {
  __shared__ double rce[256], rctx[256];
  __shared__ int rvc[256], rpc[256];
  __shared__ int ga[16], gp[16], gc[16];
  __shared__ int gdsh;
  __shared__ float qs[4]; __shared__ int qc[4];
  const int tid = threadIdx.x, lane = tid & 63, wid = tid >> 6;

  rce[tid]  = ws->ce_part[tid];
  rctx[tid] = ws->ctx_part[tid];
  rvc[tid]  = ws->ce_cnt[tid];
  rpc[tid]  = ws->ctx_cnt[tid];
  __syncthreads();
  for (int s = 128; s > 0; s >>= 1) {
    if (tid < s) {
      rce[tid] += rce[tid + s]; rctx[tid] += rctx[tid + s];
      rvc[tid] += rvc[tid + s]; rpc[tid] += rpc[tid + s];
    }
    __syncthreads();
  }

  if (tid < 16) {
    int m1 = BIGI, m2 = BIGI, cnt = 0;
    for (int bb = 0; bb < NBLK_SCAN; ++bb) {
      int x = ws->blk_a[bb][tid];
      if (x < m1) { m2 = m1; m1 = x; } else if (x < m2) { m2 = x; }
      int y = ws->blk_p[bb][tid];
      if (y < m1) { m2 = m1; m1 = y; } else if (y < m2) { m2 = y; }
      cnt += ws->blk_c[bb][tid];
    }
    ga[tid] = m1; gp[tid] = m2; gc[tid] = cnt;
  }
  if (tid == 16) {
    int d = BIGI;
    for (int bb = 0; bb < NBLK_SCAN; ++bb) d = min(d, ws->blk_d[bb]);
    gdsh = d;
  }
  __syncthreads();

  const int gd = gdsh;
  float qsum = 0.f; int qcnt = 0;
  for (int tt = 0; tt < 4; ++tt) {
    int t = wid * 4 + tt;
    int a = ga[t], p = gp[t], c = gc[t];
    int nmin = BIGI;
#pragma unroll
    for (int u = 0; u < 16; ++u) if (u != t) nmin = min(nmin, ga[u]);
    bool ok = (c >= 2) && (nmin < BIGI) && (gd < BIGI);
    if (ok) {
      const float* A  = emb + (size_t)min(a, NT - 1) * HD;
      const float* P  = emb + (size_t)min(p, NT - 1) * HD;
      const float* Ng = emb + (size_t)min(nmin, NT - 1) * HD;
      const float* D  = emb + (size_t)min(gd, NT - 1) * HD;
      float sap = 0.f, san = 0.f, sad = 0.f;
#pragma unroll
      for (int j = 0; j < 6; ++j) {
        int idx = lane + 64 * j;
        float av = A[idx];
        float d1 = av - P[idx] + 1e-6f;  sap = fmaf(d1, d1, sap);
        float d2 = av - Ng[idx] + 1e-6f; san = fmaf(d2, d2, san);
        float d3 = av - D[idx] + 1e-6f;  sad = fmaf(d3, d3, sad);
      }
#pragma unroll
      for (int off = 32; off; off >>= 1) {
        sap += __shfl_xor(sap, off, 64);
        san += __shfl_xor(san, off, 64);
        sad += __shfl_xor(sad, off, 64);
      }
      float pd = sqrtf(sap), nd = sqrtf(san), dd = sqrtf(sad);
      qsum += fmaxf(pd - nd + 1.0f, 0.f) + fmaxf(pd - dd + 2.0f, 0.f);
      qcnt += 1;
    }
  }
  if (lane == 0) { qs[wid] = qsum; qc[wid] = qcnt; }
  __syncthreads();
  if (tid == 0) {
    double tq = (double)qs[0] + qs[1] + qs[2] + qs[3];
    int tqc = qc[0] + qc[1] + qc[2] + qc[3];
    double ce   = rce[0] / (double)max(rvc[0], 1);
    double ctx  = (rpc[0] > 0) ? rctx[0] / (double)rpc[0] : 0.0;
    double quad = (tqc > 0) ? tq / (double)tqc : 0.0;
    out[0] = (float)(ce + 0.5 * quad + 0.1 * ctx);
  }
}

extern "C" void kernel_launch(void* const* d_in, const int* in_sizes, int n_in,
                              void* d_out, int out_size, void* d_ws, size_t ws_size,
                              hipStream_t stream) {
  const float* emb    = (const float*)d_in[0];
  const float* cw     = (const float*)d_in[1];
  const float* cb     = (const float*)d_in[2];
  const int*   labels = (const int*)d_in[3];
  const int*   mask   = (const int*)d_in[4];
  WS* ws = (WS*)d_ws;
  float* out = (float*)d_out;

  k_scan <<<NBLK_SCAN, 256, 0, stream>>>(labels, mask, ws);
  k_main <<<NBLK_MAIN, 256, 0, stream>>>(emb, cw, cb, labels, ws);
  k_final<<<1, 256, 0, stream>>>(emb, ws, out);
}

// Round 7
// 36.366 us; speedup vs baseline: 3.0619x; 1.2485x over previous
//
#include <hip/hip_runtime.h>

#define NL 17
#define IGN (-100)
#define HD 384
#define NSEQ 1024
#define NT 65536
#define BIGI NT
#define TPB 256
#define NBLK (NT / TPB)        // 256
#define NCHUNK 12              // 384 / 32 cols
#define CF4 8                  // float4 per row per chunk

typedef unsigned int u32;
typedef __attribute__((ext_vector_type(8))) short bf16x8;
typedef __attribute__((ext_vector_type(16))) float f32x16;

#define GLOAD_LDS16(g, l) __builtin_amdgcn_global_load_lds(                    \
    (const __attribute__((address_space(1))) u32*)(g),                         \
    (__attribute__((address_space(3))) u32*)(l), 16, 0, 0)

__device__ __forceinline__ u32 cvtpk(float lo, float hi) {
  u32 u;
  asm("v_cvt_pk_bf16_f32 %0, %1, %2" : "=v"(u) : "v"(lo), "v"(hi));
  return u;
}

struct WS {
  float ce_part[NBLK];
  float ctx_part[NBLK];
  int   ce_cnt[NBLK];
  int   ctx_cnt[NBLK];
  int   blk_a[NBLK][16];
  int   blk_p[NBLK][16];
  int   blk_c[NBLK][16];
  int   blk_d[NBLK];
};

// ---------------- main: quad-buffered gload_lds + MFMA + fused label scan ----------------
__global__ __launch_bounds__(256, 1) void k_main(const float* __restrict__ emb,
                                                 const float* __restrict__ cw,
                                                 const float* __restrict__ cb,
                                                 const int* __restrict__ labels,
                                                 const int* __restrict__ mask,
                                                 WS* __restrict__ ws) {
  __shared__ float4 tile[4][TPB * CF4];   // 4 x 32 KB, linear (gload_lds dest)
  __shared__ float4 sW4[NL * (HD / 4)];   // 25.5 KB, granule-swizzled W
  __shared__ float sce[4], sctx[4];
  __shared__ int   svc[4], spc[4];
  __shared__ float sbctx;
  __shared__ int   sbcnt;
  __shared__ int   sla[16], slp[16], slc[16], sld;

  const int tid = threadIdx.x, lane = tid & 63, wid = tid >> 6;
  const int b = blockIdx.x;
  const int token = b * TPB + tid;

  // ---- W -> LDS (once), granule-swizzled: phys q = q ^ (c&7); scan-LDS init ----
  const float4* cw4 = (const float4*)cw;
  for (int i = tid; i < NL * (HD / 4); i += TPB) {
    int c = i / (HD / 4), q = i % (HD / 4);
    sW4[c * (HD / 4) + (q ^ (c & 7))] = cw4[i];
  }
  if (tid < 16) { sla[tid] = BIGI; slp[tid] = BIGI; slc[tid] = 0; }
  if (tid == 16) sld = BIGI;
  __syncthreads();   // lgkm drained (no DMA outstanding yet)

  // ---- staging geometry (round-5/6 proven) ----
  const int rb  = tid >> 3;
  const int c4  = tid & 7;
  const int gc4 = c4 ^ (rb & 7);          // pre-swizzled source column
  const float* src0 = emb + (size_t)b * TPB * HD + (size_t)rb * HD + gc4 * 4;
  const int wbase = __builtin_amdgcn_readfirstlane(wid * 64);

  // issue chunks 0 and 1 (16 outstanding)
#pragma unroll
  for (int k = 0; k < CF4; ++k)
    GLOAD_LDS16(src0 + (size_t)k * 32 * HD, &tile[0][k * 256 + wbase]);
#pragma unroll
  for (int k = 0; k < CF4; ++k)
    GLOAD_LDS16(src0 + 32 + (size_t)k * 32 * HD, &tile[1][k * 256 + wbase]);

  // ---- MFMA geometry ----
  const int cls = lane & 31;
  const int kh  = lane >> 5;
  const int clsS = (cls < NL) ? cls : 0;
  const int row0 = wid * 64 + (lane & 31);
  const int row1 = row0 + 32;
  const int r0 = tid;
  const int r1 = (tid < TPB - 1) ? tid + 1 : tid;
  const int x0 = r0 & 7, x1 = r1 & 7;

  f32x16 d0 = {0.f}, d1 = {0.f};
  float ctxacc = 0.f;

  auto bfrag = [&](const float4* tb, int row, int s) -> bf16x8 {
    int g0 = (s * 4 + kh * 2) ^ (row & 7);
    int g1 = (s * 4 + kh * 2 + 1) ^ (row & 7);
    float4 f0 = tb[(row << 3) | g0];
    float4 f1 = tb[(row << 3) | g1];
    union { u32 u[4]; bf16x8 v; } X;
    X.u[0] = cvtpk(f0.x, f0.y); X.u[1] = cvtpk(f0.z, f0.w);
    X.u[2] = cvtpk(f1.x, f1.y); X.u[3] = cvtpk(f1.z, f1.w);
    return X.v;
  };

  auto afrag = [&](int ch, int s) -> bf16x8 {
    union { u32 u[4]; bf16x8 v; } X;
    if (cls < NL) {
      int qa = (ch * 2 + s) * 4 + kh * 2;
      float4 f0 = sW4[clsS * (HD / 4) + ((qa) ^ (cls & 7))];
      float4 f1 = sW4[clsS * (HD / 4) + ((qa + 1) ^ (cls & 7))];
      X.u[0] = cvtpk(f0.x, f0.y); X.u[1] = cvtpk(f0.z, f0.w);
      X.u[2] = cvtpk(f1.x, f1.y); X.u[3] = cvtpk(f1.z, f1.w);
    } else {
      X.u[0] = 0; X.u[1] = 0; X.u[2] = 0; X.u[3] = 0;
    }
    return X.v;
  };

  auto compute = [&](int ch, const float4* tb) {
#pragma unroll
    for (int q = 0; q < CF4; ++q) {
      float4 a  = tb[(r0 << 3) | (q ^ x0)];
      float4 nb = tb[(r1 << 3) | (q ^ x1)];
      float e0 = a.x - nb.x, e1 = a.y - nb.y, e2 = a.z - nb.z, e3 = a.w - nb.w;
      ctxacc = fmaf(e0, e0, fmaf(e1, e1, fmaf(e2, e2, fmaf(e3, e3, ctxacc))));
    }
    bf16x8 a0 = afrag(ch, 0), a1 = afrag(ch, 1);
    bf16x8 b00 = bfrag(tb, row0, 0), b01 = bfrag(tb, row0, 1);
    bf16x8 b10 = bfrag(tb, row1, 0), b11 = bfrag(tb, row1, 1);
    d0 = __builtin_amdgcn_mfma_f32_32x32x16_bf16(a0, b00, d0, 0, 0, 0);
    d0 = __builtin_amdgcn_mfma_f32_32x32x16_bf16(a1, b01, d0, 0, 0, 0);
    d1 = __builtin_amdgcn_mfma_f32_32x32x16_bf16(a0, b10, d1, 0, 0, 0);
    d1 = __builtin_amdgcn_mfma_f32_32x32x16_bf16(a1, b11, d1, 0, 0, 0);
  };

  // main loop: 2-deep prefetch, quad buffer, ONE barrier per chunk
#pragma unroll 1
  for (int ch = 0; ch < NCHUNK - 2; ++ch) {
    const float* srcn = src0 + (size_t)(ch + 2) * 32;
    float4* dstb = tile[(ch + 2) & 3];
#pragma unroll
    for (int k = 0; k < CF4; ++k)
      GLOAD_LDS16(srcn + (size_t)k * 32 * HD, &dstb[k * 256 + wbase]);
    asm volatile("s_waitcnt vmcnt(16)" ::: "memory");   // chunk ch's 8 complete
    __builtin_amdgcn_sched_barrier(0);
    __builtin_amdgcn_s_barrier();
    __builtin_amdgcn_sched_barrier(0);
    compute(ch, tile[ch & 3]);
  }
  asm volatile("s_waitcnt vmcnt(8)" ::: "memory");
  __builtin_amdgcn_sched_barrier(0);
  __builtin_amdgcn_s_barrier();
  __builtin_amdgcn_sched_barrier(0);
  compute(NCHUNK - 2, tile[(NCHUNK - 2) & 3]);
  asm volatile("s_waitcnt vmcnt(0)" ::: "memory");
  __builtin_amdgcn_sched_barrier(0);
  __builtin_amdgcn_s_barrier();
  __builtin_amdgcn_sched_barrier(0);
  compute(NCHUNK - 1, tile[(NCHUNK - 1) & 3]);
  __syncthreads();

  // ---- D -> LDS logits [256][21] ----
  float* logit = (float*)&tile[0][0];
#pragma unroll
  for (int r = 0; r < 16; ++r) {
    int row = (r & 3) + 8 * (r >> 2) + 4 * kh;
    if (row < NL) {
      logit[(wid * 64 + (lane & 31)) * 21 + row] = d0[r];
      logit[(wid * 64 + 32 + (lane & 31)) * 21 + row] = d1[r];
    }
  }
  __syncthreads();

  // ---- fused label scan, phase A ----
  int lb = labels[token];
  int mk = mask[token];
  int lbm = (mk > 0) ? lb : IGN;
  if (lbm == 0) atomicMin(&sld, token);
  else if (lbm >= 1 && lbm < NL) { atomicMin(&sla[lbm - 1], token); atomicAdd(&slc[lbm - 1], 1); }
  __syncthreads();
  // phase B (second-min) — read sla after sync
  if (lbm >= 1 && lbm < NL && token > sla[lbm - 1]) atomicMin(&slp[lbm - 1], token);

  // ---- softmax + CE + ctx pair ----
  float lg[NL];
#pragma unroll
  for (int c = 0; c < NL; ++c) lg[c] = logit[tid * 21 + c] + cb[c];
  float m = lg[0];
#pragma unroll
  for (int c = 1; c < NL; ++c) m = fmaxf(m, lg[c]);
  float s = 0.f;
#pragma unroll
  for (int c = 0; c < NL; ++c) s += __expf(lg[c] - m);
  float lse = m + __logf(s);
  int safe = (lb == IGN) ? 0 : lb;
  float ll = 0.f;
#pragma unroll
  for (int c = 0; c < NL; ++c) ll = (c == safe) ? lg[c] : ll;
  bool valid = (lb != IGN);
  float cev = valid ? (lse - ll) : 0.f;

  int nlb = (tid < TPB - 1) ? labels[token + 1] : IGN;
  bool pair = (tid < TPB - 1) && valid && (lb == nlb) && (lb > 0);
  float ctxv = pair ? ctxacc * (1.0f / HD) : 0.f;

  unsigned long long bv = __ballot(valid);
  unsigned long long bp = __ballot(pair);
#pragma unroll
  for (int off = 32; off; off >>= 1) {
    cev  += __shfl_xor(cev, off, 64);
    ctxv += __shfl_xor(ctxv, off, 64);
  }
  if (lane == 0) { sce[wid] = cev; sctx[wid] = ctxv; svc[wid] = __popcll(bv); spc[wid] = __popcll(bp); }

  if (wid == 3) {   // cross-block boundary pair
    int t = b * TPB + TPB - 1;
    float bc = 0.f; int bn = 0;
    if (((t + 1) & (NSEQ - 1)) != 0) {
      int l0 = labels[t], l1 = labels[t + 1];
      if (l0 != IGN && l0 == l1 && l0 > 0) {
        const float* ra = emb + (size_t)t * HD;
        const float* rbp = ra + HD;
        float a = 0.f;
#pragma unroll
        for (int j = 0; j < 6; ++j) {
          float dd = ra[lane + 64 * j] - rbp[lane + 64 * j];
          a = fmaf(dd, dd, a);
        }
#pragma unroll
        for (int off = 32; off; off >>= 1) a += __shfl_xor(a, off, 64);
        bc = a * (1.0f / HD); bn = 1;
      }
    }
    if (lane == 0) { sbctx = bc; sbcnt = bn; }
  }
  __syncthreads();
  if (tid < 16) {
    ws->blk_a[b][tid] = sla[tid];
    ws->blk_p[b][tid] = slp[tid];
    ws->blk_c[b][tid] = slc[tid];
  }
  if (tid == 16) ws->blk_d[b] = sld;
  if (tid == 0) {
    ws->ce_part[b]  = sce[0] + sce[1] + sce[2] + sce[3];
    ws->ce_cnt[b]   = svc[0] + svc[1] + svc[2] + svc[3];
    ws->ctx_part[b] = sctx[0] + sctx[1] + sctx[2] + sctx[3] + sbctx;
    ws->ctx_cnt[b]  = spc[0] + spc[1] + spc[2] + spc[3] + sbcnt;
  }
}

// ---------------- finalize ----------------
__global__ __launch_bounds__(256) void k_final(const float* __restrict__ emb,
                                               WS* __restrict__ ws,
                                               float* __restrict__ out) {
  __shared__ double rce[256], rctx[256];
  __shared__ int rvc[256], rpc[256], rd[256];
  __shared__ int M1[256], M2[256], CN[256];
  __shared__ int ga[16], gp[16], gc[16];
  __shared__ float qs[4]; __shared__ int qc[4];
  const int tid = threadIdx.x, lane = tid & 63, wid = tid >> 6;

  rce[tid]  = ws->ce_part[tid];
  rctx[tid] = ws->ctx_part[tid];
  rvc[tid]  = ws->ce_cnt[tid];
  rpc[tid]  = ws->ctx_cnt[tid];
  rd[tid]   = ws->blk_d[tid];

  // per-segment two-smallest merge: tid = seg*16 + type
  {
    const int type = tid & 15, seg = tid >> 4;
    int m1 = BIGI, m2 = BIGI, cnt = 0;
#pragma unroll 4
    for (int k = 0; k < 16; ++k) {
      int bb = seg * 16 + k;
      int x = ws->blk_a[bb][type];
      if (x < m1) { m2 = m1; m1 = x; } else if (x < m2) { m2 = x; }
      int y = ws->blk_p[bb][type];
      if (y < m1) { m2 = m1; m1 = y; } else if (y < m2) { m2 = y; }
      cnt += ws->blk_c[bb][type];
    }
    M1[tid] = m1; M2[tid] = m2; CN[tid] = cnt;
  }
  __syncthreads();
  for (int s = 128; s > 0; s >>= 1) {
    if (tid < s) {
      rce[tid] += rce[tid + s]; rctx[tid] += rctx[tid + s];
      rvc[tid] += rvc[tid + s]; rpc[tid] += rpc[tid + s];
      rd[tid] = min(rd[tid], rd[tid + s]);
    }
    __syncthreads();
  }
  if (tid < 16) {   // merge 16 segments per type
    int m1 = BIGI, m2 = BIGI, cnt = 0;
    for (int seg = 0; seg < 16; ++seg) {
      int a1 = M1[seg * 16 + tid], a2 = M2[seg * 16 + tid];
      int n1 = min(m1, a1);
      int n2 = min(max(m1, a1), min(m2, a2));
      m1 = n1; m2 = n2;
      cnt += CN[seg * 16 + tid];
    }
    ga[tid] = m1; gp[tid] = m2; gc[tid] = cnt;
  }
  __syncthreads();

  const int gd = rd[0];
  float qsum = 0.f; int qcnt = 0;
  for (int tt = 0; tt < 4; ++tt) {
    int t = wid * 4 + tt;
    int a = ga[t], p = gp[t], c = gc[t];
    int nmin = BIGI;
#pragma unroll
    for (int u = 0; u < 16; ++u) if (u != t) nmin = min(nmin, ga[u]);
    bool ok = (c >= 2) && (nmin < BIGI) && (gd < BIGI);
    if (ok) {
      const float* A  = emb + (size_t)min(a, NT - 1) * HD;
      const float* P  = emb + (size_t)min(p, NT - 1) * HD;
      const float* Ng = emb + (size_t)min(nmin, NT - 1) * HD;
      const float* D  = emb + (size_t)min(gd, NT - 1) * HD;
      float sap = 0.f, san = 0.f, sad = 0.f;
#pragma unroll
      for (int j = 0; j < 6; ++j) {
        int idx = lane + 64 * j;
        float av = A[idx];
        float d1 = av - P[idx] + 1e-6f;  sap = fmaf(d1, d1, sap);
        float d2 = av - Ng[idx] + 1e-6f; san = fmaf(d2, d2, san);
        float d3 = av - D[idx] + 1e-6f;  sad = fmaf(d3, d3, sad);
      }
#pragma unroll
      for (int off = 32; off; off >>= 1) {
        sap += __shfl_xor(sap, off, 64);
        san += __shfl_xor(san, off, 64);
        sad += __shfl_xor(sad, off, 64);
      }
      float pd = sqrtf(sap), nd = sqrtf(san), dd = sqrtf(sad);
      qsum += fmaxf(pd - nd + 1.0f, 0.f) + fmaxf(pd - dd + 2.0f, 0.f);
      qcnt += 1;
    }
  }
  if (lane == 0) { qs[wid] = qsum; qc[wid] = qcnt; }
  __syncthreads();
  if (tid == 0) {
    double tq = (double)qs[0] + qs[1] + qs[2] + qs[3];
    int tqc = qc[0] + qc[1] + qc[2] + qc[3];
    double ce   = rce[0] / (double)max(rvc[0], 1);
    double ctx  = (rpc[0] > 0) ? rctx[0] / (double)rpc[0] : 0.0;
    double quad = (tqc > 0) ? tq / (double)tqc : 0.0;
    out[0] = (float)(ce + 0.5 * quad + 0.1 * ctx);
  }
}

extern "C" void kernel_launch(void* const* d_in, const int* in_sizes, int n_in,
                              void* d_out, int out_size, void* d_ws, size_t ws_size,
                              hipStream_t stream) {
  const float* emb    = (const float*)d_in[0];
  const float* cw     = (const float*)d_in[1];
  const float* cb     = (const float*)d_in[2];
  const int*   labels = (const int*)d_in[3];
  const int*   mask   = (const int*)d_in[4];
  WS* ws = (WS*)d_ws;
  float* out = (float*)d_out;

  k_main <<<NBLK, 256, 0, stream>>>(emb, cw, cb, labels, mask, ws);
  k_final<<<1, 256, 0, stream>>>(emb, ws, out);
}